// Round 5
// baseline (226.906 us; speedup 1.0000x reference)
//
#include <hip/hip_runtime.h>
#include <math.h>

#define NN 1024

typedef __attribute__((ext_vector_type(8))) short bf16x8;
typedef __attribute__((ext_vector_type(4))) short bf16x4;
typedef __attribute__((ext_vector_type(4))) float f32x4;
typedef __attribute__((ext_vector_type(2))) float f32x2;
typedef __attribute__((ext_vector_type(4))) unsigned int u32x4;

#if __has_builtin(__builtin_amdgcn_mfma_f32_16x16x16bf16_1k)
#define HAVE_MFMA16 1
#define MFMA16(a, b, c) __builtin_amdgcn_mfma_f32_16x16x16bf16_1k((a), (b), (c), 0, 0, 0)
#else
#define HAVE_MFMA16 0
#endif

__device__ __forceinline__ float sigmoidf_(float x) { return 1.0f / (1.0f + __expf(-x)); }

__device__ __forceinline__ unsigned int pk2(float a, float b) {
    return __builtin_amdgcn_perm(__float_as_uint(a) + 0x8000u,
                                 __float_as_uint(b) + 0x8000u, 0x03020706u);
}
__device__ __forceinline__ unsigned int pkcvt(float a, float b) {
#if __has_builtin(__builtin_amdgcn_cvt_pk_bf16_f32)
    return __builtin_bit_cast(unsigned int, __builtin_amdgcn_cvt_pk_bf16_f32(a, b));
#else
    return pk2(a, b);
#endif
}
__device__ __forceinline__ unsigned short f2bf_rne(float a) {
    unsigned int ua = __float_as_uint(a);
    ua += 0x7fffu + ((ua >> 16) & 1u);
    return (unsigned short)(ua >> 16);
}
__device__ __forceinline__ unsigned int pk2b(float a, float b) {
    return (unsigned int)f2bf_rne(a) | ((unsigned int)f2bf_rne(b) << 16);
}

// ---------------------------------------------------------------------------
// k_step<S0>: one recurrence step, fully self-sufficient (no k_pre, no cfg,
// no Jt). 1024 blocks x 256 threads, LB(256,4).
//  - prologue: gather J column j -> LDS jcol (4KB); (S0) gather b -> LDS bcol;
//    build per-lane MFMA context from W1/W2/W3/b2/b3 directly.
//  - S0 main loop synthesizes u[i,:] = b[i]*wbi (zero global loads);
//    S>=1 keeps the verified depth-2 float4 u-prefetch.
//  - tail identical to the verified r0 tail (S0: h==0 specialization).
// ---------------------------------------------------------------------------
template<int S0>
__global__ __launch_bounds__(256, 4) void k_step(
    const float* __restrict__ J, const float* __restrict__ b,
    const float* __restrict__ W1, const float* __restrict__ b1,
    const float* __restrict__ W2, const float* __restrict__ b2,
    const float* __restrict__ W3, const float* __restrict__ b3,
    const float* __restrict__ Wih, const float* __restrict__ bih,
    const float* __restrict__ bhh,
    const float* __restrict__ R1, const float* __restrict__ rb1,
    const float* __restrict__ R2, const float* __restrict__ rb2,
    const float* __restrict__ R3, const float* __restrict__ rb3,
    float* __restrict__ h, float* __restrict__ v,
    const float* __restrict__ ui, float* __restrict__ uo,
    float* __restrict__ out, int do_out)
{
    __shared__ float jcol[1024];
    __shared__ float bcol[1024];     // used only when S0
    __shared__ float red[128];
    __shared__ float hm[64], gbuf[96], hnb[32], tb[32];

    const int tid = threadIdx.x;
    const int w = tid >> 6;
    const int l = tid & 63;
    const int p = l & 15;
    const int q = l >> 4;
    const int j = blockIdx.x;

    // ---- stage J column (and b) into LDS ----
#pragma unroll
    for (int k = 0; k < 4; k++)
        jcol[k * 256 + tid] = J[(size_t)(k * 256 + tid) * NN + j];
    if (S0) {
#pragma unroll
        for (int k = 0; k < 4; k++)
            bcol[k * 256 + tid] = b[k * 256 + tid];
    }

    // ---- per-lane MFMA context built from weights (bit-identical to cfg) ----
    union FU { bf16x8 v; u32x4 u4; unsigned int d[4]; } w2a0, w2a1;
#pragma unroll
    for (int i = 0; i < 4; i++) {
        w2a0.d[i] = pk2b(W2[p * 32 + q * 8 + 2 * i],        W2[p * 32 + q * 8 + 2 * i + 1]);
        w2a1.d[i] = pk2b(W2[(16 + p) * 32 + q * 8 + 2 * i], W2[(16 + p) * 32 + q * 8 + 2 * i + 1]);
    }
    f32x4 b2v0, b2v1;
#pragma unroll
    for (int r = 0; r < 4; r++) { b2v0[r] = b2[q * 4 + r]; b2v1[r] = b2[16 + q * 4 + r]; }
    f32x2 wj2[4], wbi2[4];
#pragma unroll
    for (int i = 0; i < 4; i++) {
        wj2[i] = f32x2{W1[(q * 8 + 2 * i) * 67 + 64], W1[(q * 8 + 2 * i + 1) * 67 + 64]};
        if (S0)
            wbi2[i] = f32x2{W1[(q * 8 + 2 * i) * 67 + 65], W1[(q * 8 + 2 * i + 1) * 67 + 65]};
    }

#if HAVE_MFMA16
    union B4 { bf16x4 v; unsigned int d[2]; } B0a, B1a, B0b, B1b;
    B0a.d[0] = pk2b(W3[p * 32 + 4 * q + 0],      W3[p * 32 + 4 * q + 1]);
    B0a.d[1] = pk2b(W3[p * 32 + 4 * q + 2],      W3[p * 32 + 4 * q + 3]);
    B1a.d[0] = pk2b(W3[p * 32 + 16 + 4 * q + 0], W3[p * 32 + 16 + 4 * q + 1]);
    B1a.d[1] = pk2b(W3[p * 32 + 16 + 4 * q + 2], W3[p * 32 + 16 + 4 * q + 3]);
    B0b.d[0] = pk2b(W3[(16 + p) * 32 + 4 * q + 0],      W3[(16 + p) * 32 + 4 * q + 1]);
    B0b.d[1] = pk2b(W3[(16 + p) * 32 + 4 * q + 2],      W3[(16 + p) * 32 + 4 * q + 3]);
    B1b.d[0] = pk2b(W3[(16 + p) * 32 + 16 + 4 * q + 0], W3[(16 + p) * 32 + 16 + 4 * q + 1]);
    B1b.d[1] = pk2b(W3[(16 + p) * 32 + 16 + 4 * q + 2], W3[(16 + p) * 32 + 16 + 4 * q + 3]);
    f32x4 b3lo, b3hi;
#pragma unroll
    for (int r = 0; r < 4; r++) { b3lo[r] = b3[p]; b3hi[r] = b3[16 + p]; }
#else
    union FU w3a0, w3a1;
#pragma unroll
    for (int i = 0; i < 4; i++) {
        w3a0.d[i] = pk2b(W3[p * 32 + q * 8 + 2 * i],        W3[p * 32 + q * 8 + 2 * i + 1]);
        w3a1.d[i] = pk2b(W3[(16 + p) * 32 + q * 8 + 2 * i], W3[(16 + p) * 32 + q * 8 + 2 * i + 1]);
    }
    f32x4 b3v0, b3v1;
#pragma unroll
    for (int r = 0; r < 4; r++) { b3v0[r] = b3[q * 4 + r]; b3v1[r] = b3[16 + q * 4 + r]; }
    const int s0 = (p | ((l & 16) << 1)) << 2;
    const int s1 = s0 + 64;
    const bool qlo = (l & 32) == 0;
#endif

    // ---- vv2 = v[j, mm-slice] (S0: computed; else loaded) ----
    f32x2 vv2[4];
    if (S0) {
        const float bj = b[j];
#pragma unroll
        for (int i = 0; i < 4; i++) {
            int m0 = q * 8 + 2 * i;
            vv2[i] = f32x2{fmaf(bj, W1[m0 * 67 + 66], b1[m0]),
                           fmaf(bj, W1[(m0 + 1) * 67 + 66], b1[m0 + 1])};
        }
    } else {
        float4 va = *(const float4*)(v + j * 32 + q * 8);
        float4 vb = *(const float4*)(v + j * 32 + q * 8 + 4);
        vv2[0] = f32x2{va.x, va.y}; vv2[1] = f32x2{va.z, va.w};
        vv2[2] = f32x2{vb.x, vb.y}; vv2[3] = f32x2{vb.z, vb.w};
    }

    f32x4 acc0 = {0.f, 0.f, 0.f, 0.f}, acc1 = {0.f, 0.f, 0.f, 0.f};
    const int ibase = w * 256;

    // per-half compute: inputs s*v = (u + vv) pairs; adds jw*wj, relu, MFMAs.
    auto do_half = [&](float jw, f32x2 s0v, f32x2 s1v, f32x2 s2v, f32x2 s3v) {
        const f32x2 jw2v = {jw, jw};
        const f32x2 z2 = {0.f, 0.f};
        const f32x4 z4 = {0.f, 0.f, 0.f, 0.f};
        f32x2 x0 = jw2v * wj2[0] + s0v;
        f32x2 x1 = jw2v * wj2[1] + s1v;
        f32x2 x2 = jw2v * wj2[2] + s2v;
        f32x2 x3 = jw2v * wj2[3] + s3v;
        x0 = __builtin_elementwise_max(x0, z2);
        x1 = __builtin_elementwise_max(x1, z2);
        x2 = __builtin_elementwise_max(x2, z2);
        x3 = __builtin_elementwise_max(x3, z2);

        union BU { u32x4 u4; bf16x8 v; unsigned int d[4]; } bx;
        bx.d[0] = pkcvt(x0[0], x0[1]);
        bx.d[1] = pkcvt(x1[0], x1[1]);
        bx.d[2] = pkcvt(x2[0], x2[1]);
        bx.d[3] = pkcvt(x3[0], x3[1]);

        f32x4 c0 = __builtin_amdgcn_mfma_f32_16x16x32_bf16(w2a0.v, bx.v, b2v0, 0, 0, 0);
        f32x4 c1 = __builtin_amdgcn_mfma_f32_16x16x32_bf16(w2a1.v, bx.v, b2v1, 0, 0, 0);
        c0 = __builtin_elementwise_max(c0, z4);
        c1 = __builtin_elementwise_max(c1, z4);

#if HAVE_MFMA16
        union B4 { bf16x4 v; unsigned int d[2]; } A0, A1;
        A0.d[0] = pkcvt(c0[0], c0[1]); A0.d[1] = pkcvt(c0[2], c0[3]);
        A1.d[0] = pkcvt(c1[0], c1[1]); A1.d[1] = pkcvt(c1[2], c1[3]);

        f32x4 e0 = MFMA16(A0.v, B0a.v, b3lo);
        e0 = MFMA16(A1.v, B1a.v, e0);
        f32x4 e1 = MFMA16(A0.v, B0b.v, b3hi);
        e1 = MFMA16(A1.v, B1b.v, e1);
        acc0 = acc0 + __builtin_elementwise_max(e0, z4);
        acc1 = acc1 + __builtin_elementwise_max(e1, z4);
#else
        const int d0 = (int)pkcvt(c0[0], c0[1]);
        const int d1 = (int)pkcvt(c0[2], c0[3]);
        const int d2 = (int)pkcvt(c1[0], c1[1]);
        const int d3 = (int)pkcvt(c1[2], c1[3]);
        const int A0_ = __builtin_amdgcn_ds_bpermute(s0, d0);
        const int A1_ = __builtin_amdgcn_ds_bpermute(s0, d1);
        const int A2_ = __builtin_amdgcn_ds_bpermute(s1, d0);
        const int A3_ = __builtin_amdgcn_ds_bpermute(s1, d1);
        const int B0_ = __builtin_amdgcn_ds_bpermute(s0, d2);
        const int B1_ = __builtin_amdgcn_ds_bpermute(s0, d3);
        const int B2_ = __builtin_amdgcn_ds_bpermute(s1, d2);
        const int B3_ = __builtin_amdgcn_ds_bpermute(s1, d3);
        union BU yr;
        yr.d[0] = (unsigned)(qlo ? A0_ : B0_);
        yr.d[1] = (unsigned)(qlo ? A1_ : B1_);
        yr.d[2] = (unsigned)(qlo ? A2_ : B2_);
        yr.d[3] = (unsigned)(qlo ? A3_ : B3_);
        f32x4 e0 = __builtin_amdgcn_mfma_f32_16x16x32_bf16(w3a0.v, yr.v, b3v0, 0, 0, 0);
        f32x4 e1 = __builtin_amdgcn_mfma_f32_16x16x32_bf16(w3a1.v, yr.v, b3v1, 0, 0, 0);
        acc0 = acc0 + __builtin_elementwise_max(e0, z4);
        acc1 = acc1 + __builtin_elementwise_max(e1, z4);
#endif
    };

    __syncthreads();   // jcol/bcol ready

    if (S0) {
        // ---- step 0: u synthesized from b (no global loads in loop) ----
#pragma unroll
        for (int tt = 0; tt < 8; ++tt) {
            const int rb0 = ibase + p + 32 * tt;
            const float jwA = jcol[rb0], jwB = jcol[rb0 + 16];
            const float biA = bcol[rb0], biB = bcol[rb0 + 16];
            const f32x2 bA = {biA, biA}, bB = {biB, biB};
            do_half(jwA, bA * wbi2[0] + vv2[0], bA * wbi2[1] + vv2[1],
                         bA * wbi2[2] + vv2[2], bA * wbi2[3] + vv2[3]);
            do_half(jwB, bB * wbi2[0] + vv2[0], bB * wbi2[1] + vv2[1],
                         bB * wbi2[2] + vv2[2], bB * wbi2[3] + vv2[3]);
        }
    } else {
        // ---- steps 1-4: depth-2 float4 u-prefetch (r0-verified) ----
        const float* up = ui + (size_t)(ibase + p) * 32 + q * 8;
        float4 ua0[2], ub0[2], ua1[2], ub1[2];
#pragma unroll
        for (int s = 0; s < 2; s++) {
            ua0[s] = *(const float4*)(up + (size_t)s * 1024);
            ub0[s] = *(const float4*)(up + (size_t)s * 1024 + 4);
            ua1[s] = *(const float4*)(up + (size_t)s * 1024 + 512);
            ub1[s] = *(const float4*)(up + (size_t)s * 1024 + 516);
        }
#pragma unroll
        for (int tt = 0; tt < 8; ++tt) {
            const int rb0 = ibase + p + 32 * tt;
            const float jwA = jcol[rb0], jwB = jcol[rb0 + 16];
            const int sl = tt & 1;
            const float4 uaA = ua0[sl], ubA = ub0[sl];
            const float4 uaB = ua1[sl], ubB = ub1[sl];
            if (tt < 6) {
                const float* un = up + (size_t)(tt + 2) * 1024;
                ua0[sl] = *(const float4*)(un);
                ub0[sl] = *(const float4*)(un + 4);
                ua1[sl] = *(const float4*)(un + 512);
                ub1[sl] = *(const float4*)(un + 516);
            }
            do_half(jwA, f32x2{uaA.x, uaA.y} + vv2[0], f32x2{uaA.z, uaA.w} + vv2[1],
                         f32x2{ubA.x, ubA.y} + vv2[2], f32x2{ubA.z, ubA.w} + vv2[3]);
            do_half(jwB, f32x2{uaB.x, uaB.y} + vv2[0], f32x2{uaB.z, uaB.w} + vv2[1],
                         f32x2{ubB.x, ubB.y} + vv2[2], f32x2{ubB.z, ubB.w} + vv2[3]);
        }
    }

#if HAVE_MFMA16
    float s0r = acc0[0] + acc0[1] + acc0[2] + acc0[3];
    float s1r = acc1[0] + acc1[1] + acc1[2] + acc1[3];
    s0r += __shfl_xor(s0r, 16);  s0r += __shfl_xor(s0r, 32);
    s1r += __shfl_xor(s1r, 16);  s1r += __shfl_xor(s1r, 32);
    if (l < 16) { red[w * 32 + l] = s0r;  red[w * 32 + 16 + l] = s1r; }
#else
#pragma unroll
    for (int bit = 1; bit < 16; bit <<= 1) {
#pragma unroll
        for (int r = 0; r < 4; r++) {
            acc0[r] += __shfl_xor(acc0[r], bit);
            acc1[r] += __shfl_xor(acc1[r], bit);
        }
    }
    if (p == 0) {
#pragma unroll
        for (int r = 0; r < 4; r++) {
            red[w * 32 + q * 4 + r]      = acc0[r];
            red[w * 32 + 16 + q * 4 + r] = acc1[r];
        }
    }
#endif
    __syncthreads();

    // ---- tail: GRU + u/v refresh (+ readout) ----
    if (tid < 64) {
        float val;
        if (tid < 32) val = S0 ? 0.f : h[j * 32 + tid];
        else {
            int ss = tid - 32;
            val = red[ss] + red[32 + ss] + red[64 + ss] + red[96 + ss];
        }
        hm[tid] = val;
    }
    __syncthreads();

    if (tid < 192) {
        const int row = tid >> 1, half = tid & 1;
        const float* wr = Wih + row * 64 + half * 32;
        const float* hh = hm + half * 32;
        float acc = 0.f;
#pragma unroll
        for (int k4 = 0; k4 < 8; k4++) {
            float4 w4 = *(const float4*)(wr + 4 * k4);
            acc = fmaf(w4.x, hh[4 * k4 + 0], acc);
            acc = fmaf(w4.y, hh[4 * k4 + 1], acc);
            acc = fmaf(w4.z, hh[4 * k4 + 2], acc);
            acc = fmaf(w4.w, hh[4 * k4 + 3], acc);
        }
        acc += __shfl_xor(acc, 1);
        if (half == 0) gbuf[row] = acc + bih[row];
    }
    __syncthreads();

    if (tid < 32) {
        const int ss = tid;
        float r = sigmoidf_(gbuf[ss] + bhh[ss]);
        float z = sigmoidf_(gbuf[32 + ss] + bhh[32 + ss]);
        float n = tanhf(gbuf[64 + ss] + r * bhh[64 + ss]);
        float hn_ = (1.0f - z) * n;
        hnb[ss] = hn_;
        h[j * 32 + ss] = hn_;
    }
    __syncthreads();

    if (tid < 64) {
        const int ss = tid & 31;
        const bool isV = tid >= 32;
        const float bj = b[j];
        const float* wr = W1 + ss * 67 + (isV ? 32 : 0);
        float acc = isV ? fmaf(bj, W1[ss * 67 + 66], b1[ss]) : bj * W1[ss * 67 + 65];
#pragma unroll
        for (int k = 0; k < 32; k++) acc = fmaf(wr[k], hnb[k], acc);
        if (isV) v[j * 32 + ss] = acc;
        else     uo[j * 32 + ss] = acc;
    }

    if (do_out) {
        __syncthreads();
        if (tid < 32) {
            float a = rb1[tid];
            const float* rr = R1 + tid * 32;
#pragma unroll 8
            for (int k = 0; k < 32; k++) a = fmaf(rr[k], hnb[k], a);
            gbuf[tid] = fmaxf(a, 0.f);
        }
        __syncthreads();
        if (tid < 32) {
            float a = rb2[tid];
            const float* rr = R2 + tid * 32;
#pragma unroll 8
            for (int k = 0; k < 32; k++) a = fmaf(rr[k], gbuf[k], a);
            tb[tid] = fmaxf(a, 0.f);
        }
        __syncthreads();
        if (tid < 2) {
            float a = rb3[tid];
            const float* rr = R3 + tid * 32;
#pragma unroll 8
            for (int k = 0; k < 32; k++) a = fmaf(rr[k], tb[k], a);
            out[j * 2 + tid] = sigmoidf_(fmaxf(a, 0.f));
        }
    }
}

// ---------------------------------------------------------------------------
extern "C" void kernel_launch(void* const* d_in, const int* in_sizes, int n_in,
                              void* d_out, int out_size, void* d_ws, size_t ws_size,
                              hipStream_t stream)
{
    const float* J   = (const float*)d_in[0];
    const float* b   = (const float*)d_in[1];
    const float* W1  = (const float*)d_in[2];
    const float* b1  = (const float*)d_in[3];
    const float* W2  = (const float*)d_in[4];
    const float* b2  = (const float*)d_in[5];
    const float* W3  = (const float*)d_in[6];
    const float* b3  = (const float*)d_in[7];
    const float* Wih = (const float*)d_in[8];
    const float* bih = (const float*)d_in[9];
    const float* bhh = (const float*)d_in[10];
    const float* R1  = (const float*)d_in[11];
    const float* rb1 = (const float*)d_in[12];
    const float* R2  = (const float*)d_in[13];
    const float* rb2 = (const float*)d_in[14];
    const float* R3  = (const float*)d_in[15];
    const float* rb3 = (const float*)d_in[16];

    float* out = (float*)d_out;
    float* ws  = (float*)d_ws;
    float* h   = ws;
    float* v   = ws + 32768;
    float* u0  = ws + 65536;
    float* u1  = ws + 98304;

    for (int s = 0; s < 5; s++) {
        const float* ui = (s & 1) ? u1 : u0;
        float*       uo = (s & 1) ? u0 : u1;
        if (s == 0)
            k_step<1><<<1024, 256, 0, stream>>>(J, b, W1, b1, W2, b2, W3, b3,
                                                Wih, bih, bhh,
                                                R1, rb1, R2, rb2, R3, rb3,
                                                h, v, ui, uo, out, 0);
        else
            k_step<0><<<1024, 256, 0, stream>>>(J, b, W1, b1, W2, b2, W3, b3,
                                                Wih, bih, bhh,
                                                R1, rb1, R2, rb2, R3, rb3,
                                                h, v, ui, uo, out, (s == 4) ? 1 : 0);
    }
}

// Round 6
// 206.449 us; speedup vs baseline: 1.0991x; 1.0991x over previous
//
#include <hip/hip_runtime.h>
#include <math.h>

#define NN 1024

typedef __attribute__((ext_vector_type(8))) short bf16x8;
typedef __attribute__((ext_vector_type(4))) short bf16x4;
typedef __attribute__((ext_vector_type(4))) float f32x4;
typedef __attribute__((ext_vector_type(2))) float f32x2;
typedef __attribute__((ext_vector_type(4))) unsigned int u32x4;

#if __has_builtin(__builtin_amdgcn_mfma_f32_16x16x16bf16_1k)
#define HAVE_MFMA16 1
#define MFMA16(a, b, c) __builtin_amdgcn_mfma_f32_16x16x16bf16_1k((a), (b), (c), 0, 0, 0)
#else
#define HAVE_MFMA16 0
#endif

__device__ __forceinline__ float sigmoidf_(float x) { return 1.0f / (1.0f + __expf(-x)); }

__device__ __forceinline__ unsigned int pk2(float a, float b) {
    return __builtin_amdgcn_perm(__float_as_uint(a) + 0x8000u,
                                 __float_as_uint(b) + 0x8000u, 0x03020706u);
}
__device__ __forceinline__ unsigned int pkcvt(float a, float b) {
#if __has_builtin(__builtin_amdgcn_cvt_pk_bf16_f32)
    return __builtin_bit_cast(unsigned int, __builtin_amdgcn_cvt_pk_bf16_f32(a, b));
#else
    return pk2(a, b);
#endif
}
__device__ __forceinline__ unsigned short f2bf_rne(float a) {
    unsigned int ua = __float_as_uint(a);
    ua += 0x7fffu + ((ua >> 16) & 1u);
    return (unsigned short)(ua >> 16);
}
__device__ __forceinline__ unsigned int pk2b(float a, float b) {
    return (unsigned int)f2bf_rne(a) | ((unsigned int)f2bf_rne(b) << 16);
}

// ---------------------------------------------------------------------------
// Hybrid (r0 x r5), 5 dispatches total:
//  step 0 (S0=1): gather J column j -> LDS (pays the uncoalesced gather ONCE),
//    write it to Jt row j (coalesced) for later steps, synthesize
//    u[i,:] = b[i]*wbi on the fly (no u read), h0 == 0 specialization.
//  steps 1-4 (S0=0): r0-verified fast path — coalesced Jt-row reads +
//    depth-2 float4 u-prefetch.
//  Both: per-block MFMA context built directly from weights (no cfg array,
//  no k_pre). 1024 blocks x 256 threads, LB(256,4).
// ---------------------------------------------------------------------------
template<int S0>
__global__ __launch_bounds__(256, 4) void k_step(
    const float* __restrict__ J, const float* __restrict__ b,
    const float* __restrict__ W1, const float* __restrict__ b1,
    const float* __restrict__ W2, const float* __restrict__ b2,
    const float* __restrict__ W3, const float* __restrict__ b3,
    const float* __restrict__ Wih, const float* __restrict__ bih,
    const float* __restrict__ bhh,
    const float* __restrict__ R1, const float* __restrict__ rb1,
    const float* __restrict__ R2, const float* __restrict__ rb2,
    const float* __restrict__ R3, const float* __restrict__ rb3,
    float* __restrict__ Jt, float* __restrict__ h, float* __restrict__ v,
    const float* __restrict__ ui, float* __restrict__ uo,
    float* __restrict__ out, int do_out)
{
    __shared__ float jcol[1024];     // used only when S0
    __shared__ float bcol[1024];     // used only when S0
    __shared__ float red[128];
    __shared__ float hm[64], gbuf[96], hnb[32], tb[32];

    const int tid = threadIdx.x;
    const int w = tid >> 6;
    const int l = tid & 63;
    const int p = l & 15;
    const int q = l >> 4;
    const int j = blockIdx.x;

    // ---- S0: stage J column j and b into LDS ----
    if (S0) {
#pragma unroll
        for (int k = 0; k < 4; k++)
            jcol[k * 256 + tid] = J[(size_t)(k * 256 + tid) * NN + j];
#pragma unroll
        for (int k = 0; k < 4; k++)
            bcol[k * 256 + tid] = b[k * 256 + tid];
    }

    // ---- per-lane MFMA context built from weights (bit-identical to cfg) ----
    union FU { bf16x8 v; u32x4 u4; unsigned int d[4]; } w2a0, w2a1;
#pragma unroll
    for (int i = 0; i < 4; i++) {
        w2a0.d[i] = pk2b(W2[p * 32 + q * 8 + 2 * i],        W2[p * 32 + q * 8 + 2 * i + 1]);
        w2a1.d[i] = pk2b(W2[(16 + p) * 32 + q * 8 + 2 * i], W2[(16 + p) * 32 + q * 8 + 2 * i + 1]);
    }
    f32x4 b2v0, b2v1;
#pragma unroll
    for (int r = 0; r < 4; r++) { b2v0[r] = b2[q * 4 + r]; b2v1[r] = b2[16 + q * 4 + r]; }
    f32x2 wj2[4], wbi2[4];
#pragma unroll
    for (int i = 0; i < 4; i++) {
        wj2[i] = f32x2{W1[(q * 8 + 2 * i) * 67 + 64], W1[(q * 8 + 2 * i + 1) * 67 + 64]};
        if (S0)
            wbi2[i] = f32x2{W1[(q * 8 + 2 * i) * 67 + 65], W1[(q * 8 + 2 * i + 1) * 67 + 65]};
    }

#if HAVE_MFMA16
    union B4 { bf16x4 v; unsigned int d[2]; } B0a, B1a, B0b, B1b;
    B0a.d[0] = pk2b(W3[p * 32 + 4 * q + 0],      W3[p * 32 + 4 * q + 1]);
    B0a.d[1] = pk2b(W3[p * 32 + 4 * q + 2],      W3[p * 32 + 4 * q + 3]);
    B1a.d[0] = pk2b(W3[p * 32 + 16 + 4 * q + 0], W3[p * 32 + 16 + 4 * q + 1]);
    B1a.d[1] = pk2b(W3[p * 32 + 16 + 4 * q + 2], W3[p * 32 + 16 + 4 * q + 3]);
    B0b.d[0] = pk2b(W3[(16 + p) * 32 + 4 * q + 0],      W3[(16 + p) * 32 + 4 * q + 1]);
    B0b.d[1] = pk2b(W3[(16 + p) * 32 + 4 * q + 2],      W3[(16 + p) * 32 + 4 * q + 3]);
    B1b.d[0] = pk2b(W3[(16 + p) * 32 + 16 + 4 * q + 0], W3[(16 + p) * 32 + 16 + 4 * q + 1]);
    B1b.d[1] = pk2b(W3[(16 + p) * 32 + 16 + 4 * q + 2], W3[(16 + p) * 32 + 16 + 4 * q + 3]);
    f32x4 b3lo, b3hi;
#pragma unroll
    for (int r = 0; r < 4; r++) { b3lo[r] = b3[p]; b3hi[r] = b3[16 + p]; }
#else
    union FU w3a0, w3a1;
#pragma unroll
    for (int i = 0; i < 4; i++) {
        w3a0.d[i] = pk2b(W3[p * 32 + q * 8 + 2 * i],        W3[p * 32 + q * 8 + 2 * i + 1]);
        w3a1.d[i] = pk2b(W3[(16 + p) * 32 + q * 8 + 2 * i], W3[(16 + p) * 32 + q * 8 + 2 * i + 1]);
    }
    f32x4 b3v0, b3v1;
#pragma unroll
    for (int r = 0; r < 4; r++) { b3v0[r] = b3[q * 4 + r]; b3v1[r] = b3[16 + q * 4 + r]; }
    const int s0 = (p | ((l & 16) << 1)) << 2;
    const int s1 = s0 + 64;
    const bool qlo = (l & 32) == 0;
#endif

    // ---- vv2 = v[j, mm-slice] (S0: computed; else loaded) ----
    f32x2 vv2[4];
    if (S0) {
        const float bj = b[j];
#pragma unroll
        for (int i = 0; i < 4; i++) {
            int m0 = q * 8 + 2 * i;
            vv2[i] = f32x2{fmaf(bj, W1[m0 * 67 + 66], b1[m0]),
                           fmaf(bj, W1[(m0 + 1) * 67 + 66], b1[m0 + 1])};
        }
    } else {
        float4 va = *(const float4*)(v + j * 32 + q * 8);
        float4 vb = *(const float4*)(v + j * 32 + q * 8 + 4);
        vv2[0] = f32x2{va.x, va.y}; vv2[1] = f32x2{va.z, va.w};
        vv2[2] = f32x2{vb.x, vb.y}; vv2[3] = f32x2{vb.z, vb.w};
    }

    f32x4 acc0 = {0.f, 0.f, 0.f, 0.f}, acc1 = {0.f, 0.f, 0.f, 0.f};
    const int ibase = w * 256;

    // per-half compute: inputs s*v = (u + vv) pairs; adds jw*wj, relu, MFMAs.
    auto do_half = [&](float jw, f32x2 s0v, f32x2 s1v, f32x2 s2v, f32x2 s3v) {
        const f32x2 jw2v = {jw, jw};
        const f32x2 z2 = {0.f, 0.f};
        const f32x4 z4 = {0.f, 0.f, 0.f, 0.f};
        f32x2 x0 = jw2v * wj2[0] + s0v;
        f32x2 x1 = jw2v * wj2[1] + s1v;
        f32x2 x2 = jw2v * wj2[2] + s2v;
        f32x2 x3 = jw2v * wj2[3] + s3v;
        x0 = __builtin_elementwise_max(x0, z2);
        x1 = __builtin_elementwise_max(x1, z2);
        x2 = __builtin_elementwise_max(x2, z2);
        x3 = __builtin_elementwise_max(x3, z2);

        union BU { u32x4 u4; bf16x8 v; unsigned int d[4]; } bx;
        bx.d[0] = pkcvt(x0[0], x0[1]);
        bx.d[1] = pkcvt(x1[0], x1[1]);
        bx.d[2] = pkcvt(x2[0], x2[1]);
        bx.d[3] = pkcvt(x3[0], x3[1]);

        f32x4 c0 = __builtin_amdgcn_mfma_f32_16x16x32_bf16(w2a0.v, bx.v, b2v0, 0, 0, 0);
        f32x4 c1 = __builtin_amdgcn_mfma_f32_16x16x32_bf16(w2a1.v, bx.v, b2v1, 0, 0, 0);
        c0 = __builtin_elementwise_max(c0, z4);
        c1 = __builtin_elementwise_max(c1, z4);

#if HAVE_MFMA16
        union B4 { bf16x4 v; unsigned int d[2]; } A0, A1;
        A0.d[0] = pkcvt(c0[0], c0[1]); A0.d[1] = pkcvt(c0[2], c0[3]);
        A1.d[0] = pkcvt(c1[0], c1[1]); A1.d[1] = pkcvt(c1[2], c1[3]);

        f32x4 e0 = MFMA16(A0.v, B0a.v, b3lo);
        e0 = MFMA16(A1.v, B1a.v, e0);
        f32x4 e1 = MFMA16(A0.v, B0b.v, b3hi);
        e1 = MFMA16(A1.v, B1b.v, e1);
        acc0 = acc0 + __builtin_elementwise_max(e0, z4);
        acc1 = acc1 + __builtin_elementwise_max(e1, z4);
#else
        const int d0 = (int)pkcvt(c0[0], c0[1]);
        const int d1 = (int)pkcvt(c0[2], c0[3]);
        const int d2 = (int)pkcvt(c1[0], c1[1]);
        const int d3 = (int)pkcvt(c1[2], c1[3]);
        const int A0_ = __builtin_amdgcn_ds_bpermute(s0, d0);
        const int A1_ = __builtin_amdgcn_ds_bpermute(s0, d1);
        const int A2_ = __builtin_amdgcn_ds_bpermute(s1, d0);
        const int A3_ = __builtin_amdgcn_ds_bpermute(s1, d1);
        const int B0_ = __builtin_amdgcn_ds_bpermute(s0, d2);
        const int B1_ = __builtin_amdgcn_ds_bpermute(s0, d3);
        const int B2_ = __builtin_amdgcn_ds_bpermute(s1, d2);
        const int B3_ = __builtin_amdgcn_ds_bpermute(s1, d3);
        union BU yr;
        yr.d[0] = (unsigned)(qlo ? A0_ : B0_);
        yr.d[1] = (unsigned)(qlo ? A1_ : B1_);
        yr.d[2] = (unsigned)(qlo ? A2_ : B2_);
        yr.d[3] = (unsigned)(qlo ? A3_ : B3_);
        f32x4 e0 = __builtin_amdgcn_mfma_f32_16x16x32_bf16(w3a0.v, yr.v, b3v0, 0, 0, 0);
        f32x4 e1 = __builtin_amdgcn_mfma_f32_16x16x32_bf16(w3a1.v, yr.v, b3v1, 0, 0, 0);
        acc0 = acc0 + __builtin_elementwise_max(e0, z4);
        acc1 = acc1 + __builtin_elementwise_max(e1, z4);
#endif
    };

    if (S0) {
        __syncthreads();   // jcol/bcol ready
        // persist J column as Jt row j (coalesced) for steps 1-4
#pragma unroll
        for (int k = 0; k < 4; k++)
            Jt[(size_t)j * NN + k * 256 + tid] = jcol[k * 256 + tid];
        // ---- step 0: u synthesized from b (no global loads in loop) ----
#pragma unroll
        for (int tt = 0; tt < 8; ++tt) {
            const int rb0 = ibase + p + 32 * tt;
            const float jwA = jcol[rb0], jwB = jcol[rb0 + 16];
            const float biA = bcol[rb0], biB = bcol[rb0 + 16];
            const f32x2 bA = {biA, biA}, bB = {biB, biB};
            do_half(jwA, bA * wbi2[0] + vv2[0], bA * wbi2[1] + vv2[1],
                         bA * wbi2[2] + vv2[2], bA * wbi2[3] + vv2[3]);
            do_half(jwB, bB * wbi2[0] + vv2[0], bB * wbi2[1] + vv2[1],
                         bB * wbi2[2] + vv2[2], bB * wbi2[3] + vv2[3]);
        }
    } else {
        // ---- steps 1-4: r0-verified — Jt-row reads + depth-2 u prefetch ----
        const float* jp = Jt + (size_t)j * NN + ibase + p;
        const float* up = ui + (size_t)(ibase + p) * 32 + q * 8;

        float  jw0[2], jw1[2];
        float4 ua0[2], ub0[2], ua1[2], ub1[2];
#pragma unroll
        for (int s = 0; s < 2; s++) {
            jw0[s] = jp[s * 32];       jw1[s] = jp[s * 32 + 16];
            ua0[s] = *(const float4*)(up + (size_t)s * 1024);
            ub0[s] = *(const float4*)(up + (size_t)s * 1024 + 4);
            ua1[s] = *(const float4*)(up + (size_t)s * 1024 + 512);
            ub1[s] = *(const float4*)(up + (size_t)s * 1024 + 516);
        }
#pragma unroll
        for (int tt = 0; tt < 8; ++tt) {
            const int sl = tt & 1;
            const float  jwA = jw0[sl], jwB = jw1[sl];
            const float4 uaA = ua0[sl], ubA = ub0[sl];
            const float4 uaB = ua1[sl], ubB = ub1[sl];
            if (tt < 6) {
                const float* jn = jp + (tt + 2) * 32;
                const float* un = up + (size_t)(tt + 2) * 1024;
                jw0[sl] = jn[0];  jw1[sl] = jn[16];
                ua0[sl] = *(const float4*)(un);
                ub0[sl] = *(const float4*)(un + 4);
                ua1[sl] = *(const float4*)(un + 512);
                ub1[sl] = *(const float4*)(un + 516);
            }
            do_half(jwA, f32x2{uaA.x, uaA.y} + vv2[0], f32x2{uaA.z, uaA.w} + vv2[1],
                         f32x2{ubA.x, ubA.y} + vv2[2], f32x2{ubA.z, ubA.w} + vv2[3]);
            do_half(jwB, f32x2{uaB.x, uaB.y} + vv2[0], f32x2{uaB.z, uaB.w} + vv2[1],
                         f32x2{ubB.x, ubB.y} + vv2[2], f32x2{ubB.z, ubB.w} + vv2[3]);
        }
    }

#if HAVE_MFMA16
    float s0r = acc0[0] + acc0[1] + acc0[2] + acc0[3];
    float s1r = acc1[0] + acc1[1] + acc1[2] + acc1[3];
    s0r += __shfl_xor(s0r, 16);  s0r += __shfl_xor(s0r, 32);
    s1r += __shfl_xor(s1r, 16);  s1r += __shfl_xor(s1r, 32);
    if (l < 16) { red[w * 32 + l] = s0r;  red[w * 32 + 16 + l] = s1r; }
#else
#pragma unroll
    for (int bit = 1; bit < 16; bit <<= 1) {
#pragma unroll
        for (int r = 0; r < 4; r++) {
            acc0[r] += __shfl_xor(acc0[r], bit);
            acc1[r] += __shfl_xor(acc1[r], bit);
        }
    }
    if (p == 0) {
#pragma unroll
        for (int r = 0; r < 4; r++) {
            red[w * 32 + q * 4 + r]      = acc0[r];
            red[w * 32 + 16 + q * 4 + r] = acc1[r];
        }
    }
#endif
    __syncthreads();

    // ---- tail: GRU + u/v refresh (+ readout) ----
    if (tid < 64) {
        float val;
        if (tid < 32) val = S0 ? 0.f : h[j * 32 + tid];
        else {
            int ss = tid - 32;
            val = red[ss] + red[32 + ss] + red[64 + ss] + red[96 + ss];
        }
        hm[tid] = val;
    }
    __syncthreads();

    if (tid < 192) {
        const int row = tid >> 1, half = tid & 1;
        const float* wr = Wih + row * 64 + half * 32;
        const float* hh = hm + half * 32;
        float acc = 0.f;
#pragma unroll
        for (int k4 = 0; k4 < 8; k4++) {
            float4 w4 = *(const float4*)(wr + 4 * k4);
            acc = fmaf(w4.x, hh[4 * k4 + 0], acc);
            acc = fmaf(w4.y, hh[4 * k4 + 1], acc);
            acc = fmaf(w4.z, hh[4 * k4 + 2], acc);
            acc = fmaf(w4.w, hh[4 * k4 + 3], acc);
        }
        acc += __shfl_xor(acc, 1);
        if (half == 0) gbuf[row] = acc + bih[row];
    }
    __syncthreads();

    if (tid < 32) {
        const int ss = tid;
        float r = sigmoidf_(gbuf[ss] + bhh[ss]);
        float z = sigmoidf_(gbuf[32 + ss] + bhh[32 + ss]);
        float n = tanhf(gbuf[64 + ss] + r * bhh[64 + ss]);
        float hn_ = (1.0f - z) * n;
        hnb[ss] = hn_;
        h[j * 32 + ss] = hn_;
    }
    __syncthreads();

    if (tid < 64) {
        const int ss = tid & 31;
        const bool isV = tid >= 32;
        const float bj = b[j];
        const float* wr = W1 + ss * 67 + (isV ? 32 : 0);
        float acc = isV ? fmaf(bj, W1[ss * 67 + 66], b1[ss]) : bj * W1[ss * 67 + 65];
#pragma unroll
        for (int k = 0; k < 32; k++) acc = fmaf(wr[k], hnb[k], acc);
        if (isV) v[j * 32 + ss] = acc;
        else     uo[j * 32 + ss] = acc;
    }

    if (do_out) {
        __syncthreads();
        if (tid < 32) {
            float a = rb1[tid];
            const float* rr = R1 + tid * 32;
#pragma unroll 8
            for (int k = 0; k < 32; k++) a = fmaf(rr[k], hnb[k], a);
            gbuf[tid] = fmaxf(a, 0.f);
        }
        __syncthreads();
        if (tid < 32) {
            float a = rb2[tid];
            const float* rr = R2 + tid * 32;
#pragma unroll 8
            for (int k = 0; k < 32; k++) a = fmaf(rr[k], gbuf[k], a);
            tb[tid] = fmaxf(a, 0.f);
        }
        __syncthreads();
        if (tid < 2) {
            float a = rb3[tid];
            const float* rr = R3 + tid * 32;
#pragma unroll 8
            for (int k = 0; k < 32; k++) a = fmaf(rr[k], tb[k], a);
            out[j * 2 + tid] = sigmoidf_(fmaxf(a, 0.f));
        }
    }
}

// ---------------------------------------------------------------------------
extern "C" void kernel_launch(void* const* d_in, const int* in_sizes, int n_in,
                              void* d_out, int out_size, void* d_ws, size_t ws_size,
                              hipStream_t stream)
{
    const float* J   = (const float*)d_in[0];
    const float* b   = (const float*)d_in[1];
    const float* W1  = (const float*)d_in[2];
    const float* b1  = (const float*)d_in[3];
    const float* W2  = (const float*)d_in[4];
    const float* b2  = (const float*)d_in[5];
    const float* W3  = (const float*)d_in[6];
    const float* b3  = (const float*)d_in[7];
    const float* Wih = (const float*)d_in[8];
    const float* bih = (const float*)d_in[9];
    const float* bhh = (const float*)d_in[10];
    const float* R1  = (const float*)d_in[11];
    const float* rb1 = (const float*)d_in[12];
    const float* R2  = (const float*)d_in[13];
    const float* rb2 = (const float*)d_in[14];
    const float* R3  = (const float*)d_in[15];
    const float* rb3 = (const float*)d_in[16];

    float* out = (float*)d_out;
    float* ws  = (float*)d_ws;
    float* h   = ws;
    float* v   = ws + 32768;
    float* u0  = ws + 65536;
    float* u1  = ws + 98304;
    float* Jt  = ws + 131072;

    for (int s = 0; s < 5; s++) {
        const float* ui = (s & 1) ? u1 : u0;
        float*       uo = (s & 1) ? u0 : u1;
        if (s == 0)
            k_step<1><<<1024, 256, 0, stream>>>(J, b, W1, b1, W2, b2, W3, b3,
                                                Wih, bih, bhh,
                                                R1, rb1, R2, rb2, R3, rb3,
                                                Jt, h, v, ui, uo, out, 0);
        else
            k_step<0><<<1024, 256, 0, stream>>>(J, b, W1, b1, W2, b2, W3, b3,
                                                Wih, bih, bhh,
                                                R1, rb1, R2, rb2, R3, rb3,
                                                Jt, h, v, ui, uo, out, (s == 4) ? 1 : 0);
    }
}